// Round 8
// baseline (1573.054 us; speedup 1.0000x reference)
//
#include <hip/hip_runtime.h>
#include <hip/hip_bf16.h>
#include <math.h>

typedef _Float16 f16x8 __attribute__((ext_vector_type(8)));
typedef float    f32x4 __attribute__((ext_vector_type(4)));

#define B_SZ 512
#define T_SZ 2048
#define D_SZ 256

// ---------- kernel 1: W_eff = -log2e * (Wa @ Wi) in fp16; b_eff scaled too; zero ao.
__global__ __launch_bounds__(256) void prep_kernel(
    const float* __restrict__ Wa, const float* __restrict__ Wi,
    const float* __restrict__ bi, const float* __restrict__ bh,
    const float* __restrict__ ba,
    _Float16* __restrict__ Weff, float* __restrict__ beff,
    float* __restrict__ ao)
{
    const float NL2E = -1.4426950408889634f;   // -log2(e): sigmoid(s)=1/(1+exp2(NL2E*s))
    int e = blockIdx.x;      // output row (256)
    int d = threadIdx.x;     // output col (256)
    float a0 = 0.f, a1 = 0.f, a2 = 0.f, a3 = 0.f;
    #pragma unroll 4
    for (int k = 0; k < 256; k += 4) {
        a0 = fmaf(Wa[e*256 + k    ], Wi[(k    )*256 + d], a0);
        a1 = fmaf(Wa[e*256 + k + 1], Wi[(k + 1)*256 + d], a1);
        a2 = fmaf(Wa[e*256 + k + 2], Wi[(k + 2)*256 + d], a2);
        a3 = fmaf(Wa[e*256 + k + 3], Wi[(k + 3)*256 + d], a3);
    }
    Weff[e*256 + d] = (_Float16)(NL2E * ((a0 + a1) + (a2 + a3)));

    // zero ao (131072 floats; 65536 threads x 2)
    int gt = e*256 + d;
    ao[gt*2] = 0.f; ao[gt*2 + 1] = 0.f;

    __shared__ float red[4];
    float s = Wa[e*256 + d] * (bi[d] + bh[d]);
    s += __shfl_down(s, 32, 64);
    s += __shfl_down(s, 16, 64);
    s += __shfl_down(s,  8, 64);
    s += __shfl_down(s,  4, 64);
    s += __shfl_down(s,  2, 64);
    s += __shfl_down(s,  1, 64);
    if ((d & 63) == 0) red[d >> 6] = s;
    __syncthreads();
    if (d == 0) beff[e] = NL2E * (ba[e] + ((red[0] + red[1]) + (red[2] + red[3])));
}

// ---------- kernel 2: barrier-free streaming attention
// 256 blocks x 16 waves; wave = (batch, 256-row slice). Weff lives in LDS
// (swizzled, copied once). Each wave: 8 chunks of 32 rows; x loaded coalesced
// global->reg->f16 frags; 16 e-tiles x 8 ks MFMA (B-frag one ds_read_b128,
// shared by 2 row-tiles); sigmoid via exp2 (pre-scaled W); epilogue re-reads
// x fp32 from L2; atomicAdd partials into ao.
__global__ __launch_bounds__(1024, 4) void attn_kernel(
    const float* __restrict__ x,          // (B, T, D)
    const _Float16* __restrict__ Weff,    // (256, 256) pre-scaled
    const float* __restrict__ beff,       // (256) pre-scaled
    float* __restrict__ ao)               // (B, 256), pre-zeroed
{
    const int tid  = threadIdx.x;          // 0..1023
    const int wv   = tid >> 6;             // 0..15
    const int lane = tid & 63;
    const int l15  = lane & 15;
    const int lq   = lane >> 4;

    __shared__ _Float16 wlds[256 * 256];   // 128 KB, slot-swizzled
    __shared__ float    blds[256];

    // one-time cooperative copy Weff -> LDS with slot swizzle (slot ^= (e&7)<<2)
    #pragma unroll
    for (int j = 0; j < 8; ++j) {
        int chunk = tid + j * 1024;        // 0..8191 16B-chunks, coalesced
        int e = chunk >> 5;
        int s = chunk & 31;
        f16x8 v = *reinterpret_cast<const f16x8*>(&Weff[e * 256 + s * 8]);
        int s2 = s ^ ((e & 7) << 2);
        *reinterpret_cast<f16x8*>(reinterpret_cast<char*>(wlds) + e * 512 + s2 * 16) = v;
    }
    if (tid < 256) blds[tid] = beff[tid];
    __syncthreads();                       // the ONLY barrier

    const int gw     = blockIdx.x * 16 + wv;   // 0..4095
    const int b      = gw >> 3;                // batch
    const int t_base = (gw & 7) * 256;         // slice start

    const char* wbase = reinterpret_cast<const char*>(wlds);
    const float* xb   = x + (size_t)b * T_SZ * D_SZ;

    float aoc[16];
    #pragma unroll
    for (int i = 0; i < 16; ++i) aoc[i] = 0.f;

    for (int ch = 0; ch < 8; ++ch) {
        const float* xrow0 = xb + (size_t)(t_base + ch * 32) * 256;

        // ---- load A fragments: rows l15 (rt0) and l15+16 (rt1), full k=256
        const float* xr0 = xrow0 + (size_t)l15 * 256 + lq * 8;
        const float* xr1 = xr0 + 16 * 256;
        f16x8 A0[8], A1[8];
        #pragma unroll
        for (int ks = 0; ks < 8; ++ks) {
            f32x4 lo = *reinterpret_cast<const f32x4*>(xr0 + ks * 32);
            f32x4 hi = *reinterpret_cast<const f32x4*>(xr0 + ks * 32 + 4);
            f16x8 a;
            a[0] = (_Float16)lo[0]; a[1] = (_Float16)lo[1];
            a[2] = (_Float16)lo[2]; a[3] = (_Float16)lo[3];
            a[4] = (_Float16)hi[0]; a[5] = (_Float16)hi[1];
            a[6] = (_Float16)hi[2]; a[7] = (_Float16)hi[3];
            A0[ks] = a;
        }
        #pragma unroll
        for (int ks = 0; ks < 8; ++ks) {
            f32x4 lo = *reinterpret_cast<const f32x4*>(xr1 + ks * 32);
            f32x4 hi = *reinterpret_cast<const f32x4*>(xr1 + ks * 32 + 4);
            f16x8 a;
            a[0] = (_Float16)lo[0]; a[1] = (_Float16)lo[1];
            a[2] = (_Float16)lo[2]; a[3] = (_Float16)lo[3];
            a[4] = (_Float16)hi[0]; a[5] = (_Float16)hi[1];
            a[6] = (_Float16)hi[2]; a[7] = (_Float16)hi[3];
            A1[ks] = a;
        }

        // ---- 16 e-tiles
        #pragma unroll
        for (int et = 0; et < 16; ++et) {
            const int e = et * 16 + l15;
            const float be = blds[e];
            f32x4 acc0 = {be, be, be, be};     // bias folded into C-init
            f32x4 acc1 = {be, be, be, be};
            #pragma unroll
            for (int ks = 0; ks < 8; ++ks) {
                int slot = (ks * 4 + lq) ^ ((e & 7) << 2);
                f16x8 bf = *reinterpret_cast<const f16x8*>(wbase + e * 512 + slot * 16);
                acc0 = __builtin_amdgcn_mfma_f32_16x16x32_f16(A0[ks], bf, acc0, 0, 0, 0);
                acc1 = __builtin_amdgcn_mfma_f32_16x16x32_f16(A1[ks], bf, acc1, 0, 0, 0);
            }
            // epilogue: C row = lq*4 + r (+16 for rt1), col e; x re-read fp32 (L2-hot)
            const float* xe0 = xrow0 + (size_t)(lq * 4) * 256 + et * 16 + l15;
            const float* xe1 = xe0 + 16 * 256;
            float t = aoc[et];
            #pragma unroll
            for (int r = 0; r < 4; ++r) {
                float attn0 = __builtin_amdgcn_rcpf(1.f + exp2f(acc0[r]));
                float attn1 = __builtin_amdgcn_rcpf(1.f + exp2f(acc1[r]));
                t = fmaf(attn0, xe0[r * 256], t);
                t = fmaf(attn1, xe1[r * 256], t);
            }
            aoc[et] = t;
        }
    }

    // reduce across lq groups (lanes sharing l15 share e) and atomically add
    #pragma unroll
    for (int et = 0; et < 16; ++et) {
        float v = aoc[et];
        v += __shfl_xor(v, 16, 64);
        v += __shfl_xor(v, 32, 64);
        if (lq == 0) atomicAdd(&ao[b * 256 + et * 16 + l15], v);
    }
}

// ---------- kernel 3: LSTM cell (h0=c0=0 => f gate dead, W_hh dead)
// 128 blocks x 4 batches: W_ih rows loaded once per block, reused across 4 batches.
__global__ __launch_bounds__(256) void lstm_kernel(
    const float* __restrict__ ao,        // (B, 256)
    const float* __restrict__ Wih,       // (1024, 256)
    const float* __restrict__ bih,       // (1024)
    const float* __restrict__ bhh,       // (1024)
    float* __restrict__ out)             // h (B*256) | h (B*256) | c (B*256)
{
    const int b0 = blockIdx.x * 4;   // 128 blocks
    const int j  = threadIdx.x;      // 256
    __shared__ float a[4][256];
    #pragma unroll
    for (int bb = 0; bb < 4; ++bb) a[bb][j] = ao[(b0 + bb)*256 + j];
    __syncthreads();

    const float bi_ = bih[j]       + bhh[j];
    const float bg_ = bih[512 + j] + bhh[512 + j];
    const float bo_ = bih[768 + j] + bhh[768 + j];
    float gi[4], gg[4], go[4];
    #pragma unroll
    for (int bb = 0; bb < 4; ++bb) { gi[bb] = bi_; gg[bb] = bg_; go[bb] = bo_; }

    const float* wi = Wih + (size_t)j * 256;
    const float* wg = Wih + (size_t)(512 + j) * 256;
    const float* wo = Wih + (size_t)(768 + j) * 256;
    #pragma unroll 2
    for (int k = 0; k < 256; k += 4) {
        f32x4 w1 = *reinterpret_cast<const f32x4*>(wi + k);
        f32x4 w2 = *reinterpret_cast<const f32x4*>(wg + k);
        f32x4 w3 = *reinterpret_cast<const f32x4*>(wo + k);
        f32x4 av0 = *reinterpret_cast<const f32x4*>(&a[0][k]);
        f32x4 av1 = *reinterpret_cast<const f32x4*>(&a[1][k]);
        f32x4 av2 = *reinterpret_cast<const f32x4*>(&a[2][k]);
        f32x4 av3 = *reinterpret_cast<const f32x4*>(&a[3][k]);
        #pragma unroll
        for (int q = 0; q < 4; ++q) {
            gi[0] = fmaf(w1[q], av0[q], gi[0]); gg[0] = fmaf(w2[q], av0[q], gg[0]); go[0] = fmaf(w3[q], av0[q], go[0]);
            gi[1] = fmaf(w1[q], av1[q], gi[1]); gg[1] = fmaf(w2[q], av1[q], gg[1]); go[1] = fmaf(w3[q], av1[q], go[1]);
            gi[2] = fmaf(w1[q], av2[q], gi[2]); gg[2] = fmaf(w2[q], av2[q], gg[2]); go[2] = fmaf(w3[q], av2[q], go[2]);
            gi[3] = fmaf(w1[q], av3[q], gi[3]); gg[3] = fmaf(w2[q], av3[q], gg[3]); go[3] = fmaf(w3[q], av3[q], go[3]);
        }
    }

    #pragma unroll
    for (int bb = 0; bb < 4; ++bb) {
        float ig = 1.f / (1.f + __expf(-gi[bb]));
        float g  = tanhf(gg[bb]);
        float og = 1.f / (1.f + __expf(-go[bb]));
        float cc = ig * g;
        float hh = og * tanhf(cc);
        out[          (b0 + bb)*256 + j] = hh;
        out[131072 +  (b0 + bb)*256 + j] = hh;
        out[262144 +  (b0 + bb)*256 + j] = cc;
    }
}

extern "C" void kernel_launch(void* const* d_in, const int* in_sizes, int n_in,
                              void* d_out, int out_size, void* d_ws, size_t ws_size,
                              hipStream_t stream) {
    const float* x    = (const float*)d_in[0];
    const float* Wi   = (const float*)d_in[1];
    const float* bi   = (const float*)d_in[2];
    // d_in[3] = Wh (dead: h0 = 0)
    const float* bh   = (const float*)d_in[4];
    const float* Wa   = (const float*)d_in[5];
    const float* ba   = (const float*)d_in[6];
    const float* W_ih = (const float*)d_in[7];
    const float* b_ih = (const float*)d_in[8];
    // d_in[9] = W_hh (dead: h0 = 0)
    const float* b_hh = (const float*)d_in[10];

    char* ws = (char*)d_ws;
    _Float16* Weff = (_Float16*)ws;                  // 128 KB
    float*    beff = (float*)(ws + 128*1024);        // 1 KB
    float*    ao   = (float*)(ws + 132*1024);        // 512 KB

    prep_kernel<<<256, 256, 0, stream>>>(Wa, Wi, bi, bh, ba, Weff, beff, ao);
    attn_kernel<<<256, 1024, 0, stream>>>(x, Weff, beff, ao);
    lstm_kernel<<<128, 256, 0, stream>>>(ao, W_ih, b_ih, b_hh, (float*)d_out);
}

// Round 9
// 291.364 us; speedup vs baseline: 5.3989x; 5.3989x over previous
//
#include <hip/hip_runtime.h>
#include <hip/hip_bf16.h>

typedef _Float16 f16x8 __attribute__((ext_vector_type(8)));
typedef _Float16 f16x4 __attribute__((ext_vector_type(4)));
typedef float    f32x4 __attribute__((ext_vector_type(4)));

#define B_SZ 512
#define T_SZ 2048
#define D_SZ 256
#define TCHUNK 16
#define NCHUNK (T_SZ / TCHUNK)   // 128

// ---------- kernel 1: W_eff = -log2e * (Wa @ Wi) fp16; b_eff = -log2e * (Wa@(bi+bh) + ba)
// (prescale folds sigmoid's exp->exp2 conversion into the weights; r8-verified)
__global__ __launch_bounds__(256) void prep_kernel(
    const float* __restrict__ Wa, const float* __restrict__ Wi,
    const float* __restrict__ bi, const float* __restrict__ bh,
    const float* __restrict__ ba,
    _Float16* __restrict__ Weff, float* __restrict__ beff)
{
    const float NL2E = -1.4426950408889634f;   // sigmoid(s) = 1/(1+exp2(NL2E*s))
    int e = blockIdx.x;      // output row (256)
    int d = threadIdx.x;     // output col (256)
    float a0 = 0.f, a1 = 0.f, a2 = 0.f, a3 = 0.f;
    #pragma unroll 4
    for (int k = 0; k < 256; k += 4) {
        a0 = fmaf(Wa[e*256 + k    ], Wi[(k    )*256 + d], a0);
        a1 = fmaf(Wa[e*256 + k + 1], Wi[(k + 1)*256 + d], a1);
        a2 = fmaf(Wa[e*256 + k + 2], Wi[(k + 2)*256 + d], a2);
        a3 = fmaf(Wa[e*256 + k + 3], Wi[(k + 3)*256 + d], a3);
    }
    Weff[e*256 + d] = (_Float16)(NL2E * ((a0 + a1) + (a2 + a3)));

    __shared__ float red[4];
    float s = Wa[e*256 + d] * (bi[d] + bh[d]);
    s += __shfl_down(s, 32, 64);
    s += __shfl_down(s, 16, 64);
    s += __shfl_down(s,  8, 64);
    s += __shfl_down(s,  4, 64);
    s += __shfl_down(s,  2, 64);
    s += __shfl_down(s,  1, 64);
    if ((d & 63) == 0) red[d >> 6] = s;
    __syncthreads();
    if (d == 0) beff[e] = NL2E * (ba[e] + ((red[0] + red[1]) + (red[2] + red[3])));
}

// ---------- kernel 2: fused GEMM + sigmoid + sum_t attn*x -> ao (B,256)
// r5 base (proven 264us): 8 waves x 32 cols, swapped MFMA (S^T), fp16 LDS,
// double-buffer 2x8KB, reg-staged coalesced loads (r8 counters prove staging
// is mandatory for coalescing). Round-9 deltas: LOADC issued BEFORE the
// barrier (extra latency lead, loads live across it); sigmoid via exp2 with
// prescaled weights; bias folded into acc init; odd blocks run chunks in
// REVERSE order to desync the two co-resident blocks' barrier phases.
__global__ __launch_bounds__(512, 4) void attn_kernel(
    const float* __restrict__ x,          // (B, T, D)
    const _Float16* __restrict__ Weff,    // (256, 256) prescaled, row-major [e][k]
    const float* __restrict__ beff,       // (256) prescaled
    float* __restrict__ ao)               // (B, 256)
{
    const int b    = blockIdx.x;
    const int tid  = threadIdx.x;          // 0..511
    const int wave = tid >> 6;             // 0..7
    const int lane = tid & 63;
    const int l15  = lane & 15;
    const int lq   = lane >> 4;

    __shared__ _Float16 xs[2][TCHUNK * 256];  // 2 x 8 KB, swizzle: byte ^= (row&7)<<4
    char* xsb0 = reinterpret_cast<char*>(&xs[0][0]);
    char* xsb1 = reinterpret_cast<char*>(&xs[1][0]);

    // Weff fragments (A-operand after swap): lane holds Weff[e=base+l15][k=ks*32+lq*8+i]
    const int col0 = wave*32 + l15;
    const int col1 = col0 + 16;
    f16x8 bfA[8], bfB[8];
    #pragma unroll
    for (int ks = 0; ks < 8; ++ks) {
        bfA[ks] = *reinterpret_cast<const f16x8*>(&Weff[col0*256 + ks*32 + lq*8]);
        bfB[ks] = *reinterpret_cast<const f16x8*>(&Weff[col1*256 + ks*32 + lq*8]);
    }
    // bias per accumulator slot: e = wave*32 (+16) + lq*4 + r  (prescaled)
    const f32x4 bcA = *reinterpret_cast<const f32x4*>(&beff[wave*32 + lq*4]);
    const f32x4 bcB = *reinterpret_cast<const f32x4*>(&beff[wave*32 + 16 + lq*4]);

    const float* xb = x + (size_t)b * T_SZ * D_SZ;

    // chunk-order: odd blocks reverse (sum over t is order-independent) -> the
    // two co-resident blocks on a CU never phase-lock on identical addresses.
    const int rev   = b & 1;
    const int cbase = rev ? (NCHUNK - 1) : 0;
    #define CIDX(c) (rev ? (cbase - (c)) : (c))

    // staging: thread covers row = tid>>5 (0..15), 8 floats at col (tid&31)*8
    const int srow = tid >> 5;
    const int scg  = tid & 31;
    const float* srcp = xb + (size_t)srow * 256 + scg * 8;
    const int swb = (srow*512 + scg*16) ^ ((srow & 7) << 4);

    #define LOADC(R, c)                                                            \
        {                                                                          \
            const float* p = srcp + (size_t)(c) * (TCHUNK * D_SZ);                 \
            R##0 = *reinterpret_cast<const f32x4*>(p);                             \
            R##1 = *reinterpret_cast<const f32x4*>(p + 4);                         \
        }

    #define WRITE(BUF, R)                                                          \
        {                                                                          \
            f16x8 h;                                                               \
            h[0] = (_Float16)R##0[0]; h[1] = (_Float16)R##0[1];                    \
            h[2] = (_Float16)R##0[2]; h[3] = (_Float16)R##0[3];                    \
            h[4] = (_Float16)R##1[0]; h[5] = (_Float16)R##1[1];                    \
            h[6] = (_Float16)R##1[2]; h[7] = (_Float16)R##1[3];                    \
            *reinterpret_cast<f16x8*>((BUF) + swb) = h;                            \
        }

    // lgkm drain (my LDS ops done) -> barrier; does NOT drain vmcnt (prefetch lives)
    #define SYNC()                                                                 \
        {                                                                          \
            asm volatile("s_waitcnt lgkmcnt(0)" ::: "memory");                     \
            __builtin_amdgcn_sched_barrier(0);                                     \
            __builtin_amdgcn_s_barrier();                                          \
        }

    #define COMPUTE(BUF)                                                           \
        {                                                                          \
            const int aswz  = (l15 & 7) << 4;                                      \
            const int abase = l15 * 512;                                           \
            f32x4 acc0 = bcA;                                                      \
            f32x4 acc1 = bcB;                                                      \
            _Pragma("unroll")                                                      \
            for (int ks = 0; ks < 8; ++ks) {                                       \
                int ab = abase + ((ks*64 + lq*16) ^ aswz);                         \
                f16x8 a = *reinterpret_cast<const f16x8*>((BUF) + ab);             \
                acc0 = __builtin_amdgcn_mfma_f32_16x16x32_f16(bfA[ks], a, acc0, 0, 0, 0); \
                acc1 = __builtin_amdgcn_mfma_f32_16x16x32_f16(bfB[ks], a, acc1, 0, 0, 0); \
            }                                                                      \
            /* epilogue: lane has t = l15, e = wave*32 (+16) + lq*4 + r */         \
            int eb0 = abase + (((wave*64      ) + lq*8) ^ aswz);                   \
            int eb1 = abase + (((wave*64 + 32 ) + lq*8) ^ aswz);                   \
            f16x4 xq0 = *reinterpret_cast<const f16x4*>((BUF) + eb0);              \
            f16x4 xq1 = *reinterpret_cast<const f16x4*>((BUF) + eb1);              \
            _Pragma("unroll")                                                      \
            for (int r = 0; r < 4; ++r) {                                          \
                {                                                                  \
                    float attn = __builtin_amdgcn_rcpf(1.f + exp2f(acc0[r]));      \
                    ao0[r] = fmaf(attn, (float)xq0[r], ao0[r]);                    \
                }                                                                  \
                {                                                                  \
                    float attn = __builtin_amdgcn_rcpf(1.f + exp2f(acc1[r]));      \
                    ao1[r] = fmaf(attn, (float)xq1[r], ao1[r]);                    \
                }                                                                  \
            }                                                                      \
        }

    f32x4 ao0 = {0.f, 0.f, 0.f, 0.f};
    f32x4 ao1 = {0.f, 0.f, 0.f, 0.f};
    f32x4 sA0, sA1, sB0, sB1;

    LOADC(sA, CIDX(0));
    LOADC(sB, CIDX(1));

    for (int c = 0; c < NCHUNK; c += 2) {
        WRITE(xsb0, sA);                 // vmcnt-waits sA only; sA regs dead after cvt
        if (c + 2 < NCHUNK) LOADC(sA, CIDX(c + 2));   // issue BEFORE barrier
        SYNC();                          // chunk c visible to all waves
        COMPUTE(xsb0);                   // chunk c
        WRITE(xsb1, sB);                 // other buffer: safe while others compute xsb0
        if (c + 3 < NCHUNK) LOADC(sB, CIDX(c + 3));
        SYNC();                          // chunk c+1 visible
        COMPUTE(xsb1);                   // chunk c+1
    }

    // sum over t: reduce across l15 within each lq group
    #pragma unroll
    for (int m = 1; m <= 8; m <<= 1) {
        #pragma unroll
        for (int r = 0; r < 4; ++r) {
            ao0[r] += __shfl_xor(ao0[r], m, 64);
            ao1[r] += __shfl_xor(ao1[r], m, 64);
        }
    }
    if (l15 == 0) {
        *reinterpret_cast<f32x4*>(&ao[b*256 + wave*32 +      lq*4]) = ao0;
        *reinterpret_cast<f32x4*>(&ao[b*256 + wave*32 + 16 + lq*4]) = ao1;
    }

    #undef LOADC
    #undef WRITE
    #undef SYNC
    #undef COMPUTE
    #undef CIDX
}

// ---------- kernel 3: LSTM cell (h0=c0=0 => f gate dead, W_hh dead)
// 128 blocks x 4 batches: W_ih rows loaded once per block, reused across 4 batches.
__global__ __launch_bounds__(256) void lstm_kernel(
    const float* __restrict__ ao,        // (B, 256)
    const float* __restrict__ Wih,       // (1024, 256)
    const float* __restrict__ bih,       // (1024)
    const float* __restrict__ bhh,       // (1024)
    float* __restrict__ out)             // h (B*256) | h (B*256) | c (B*256)
{
    const int b0 = blockIdx.x * 4;   // 128 blocks
    const int j  = threadIdx.x;      // 256
    __shared__ float a[4][256];
    #pragma unroll
    for (int bb = 0; bb < 4; ++bb) a[bb][j] = ao[(b0 + bb)*256 + j];
    __syncthreads();

    const float bi_ = bih[j]       + bhh[j];
    const float bg_ = bih[512 + j] + bhh[512 + j];
    const float bo_ = bih[768 + j] + bhh[768 + j];
    float gi[4], gg[4], go[4];
    #pragma unroll
    for (int bb = 0; bb < 4; ++bb) { gi[bb] = bi_; gg[bb] = bg_; go[bb] = bo_; }

    const float* wi = Wih + (size_t)j * 256;
    const float* wg = Wih + (size_t)(512 + j) * 256;
    const float* wo = Wih + (size_t)(768 + j) * 256;
    #pragma unroll 2
    for (int k = 0; k < 256; k += 4) {
        f32x4 w1 = *reinterpret_cast<const f32x4*>(wi + k);
        f32x4 w2 = *reinterpret_cast<const f32x4*>(wg + k);
        f32x4 w3 = *reinterpret_cast<const f32x4*>(wo + k);
        f32x4 av0 = *reinterpret_cast<const f32x4*>(&a[0][k]);
        f32x4 av1 = *reinterpret_cast<const f32x4*>(&a[1][k]);
        f32x4 av2 = *reinterpret_cast<const f32x4*>(&a[2][k]);
        f32x4 av3 = *reinterpret_cast<const f32x4*>(&a[3][k]);
        #pragma unroll
        for (int q = 0; q < 4; ++q) {
            gi[0] = fmaf(w1[q], av0[q], gi[0]); gg[0] = fmaf(w2[q], av0[q], gg[0]); go[0] = fmaf(w3[q], av0[q], go[0]);
            gi[1] = fmaf(w1[q], av1[q], gi[1]); gg[1] = fmaf(w2[q], av1[q], gg[1]); go[1] = fmaf(w3[q], av1[q], go[1]);
            gi[2] = fmaf(w1[q], av2[q], gi[2]); gg[2] = fmaf(w2[q], av2[q], gg[2]); go[2] = fmaf(w3[q], av2[q], go[2]);
            gi[3] = fmaf(w1[q], av3[q], gi[3]); gg[3] = fmaf(w2[q], av3[q], gg[3]); go[3] = fmaf(w3[q], av3[q], go[3]);
        }
    }

    #pragma unroll
    for (int bb = 0; bb < 4; ++bb) {
        float ig = 1.f / (1.f + __expf(-gi[bb]));
        float g  = tanhf(gg[bb]);
        float og = 1.f / (1.f + __expf(-go[bb]));
        float cc = ig * g;
        float hh = og * tanhf(cc);
        out[          (b0 + bb)*256 + j] = hh;
        out[131072 +  (b0 + bb)*256 + j] = hh;
        out[262144 +  (b0 + bb)*256 + j] = cc;
    }
}

extern "C" void kernel_launch(void* const* d_in, const int* in_sizes, int n_in,
                              void* d_out, int out_size, void* d_ws, size_t ws_size,
                              hipStream_t stream) {
    const float* x    = (const float*)d_in[0];
    const float* Wi   = (const float*)d_in[1];
    const float* bi   = (const float*)d_in[2];
    // d_in[3] = Wh (dead: h0 = 0)
    const float* bh   = (const float*)d_in[4];
    const float* Wa   = (const float*)d_in[5];
    const float* ba   = (const float*)d_in[6];
    const float* W_ih = (const float*)d_in[7];
    const float* b_ih = (const float*)d_in[8];
    // d_in[9] = W_hh (dead: h0 = 0)
    const float* b_hh = (const float*)d_in[10];

    char* ws = (char*)d_ws;
    _Float16* Weff = (_Float16*)ws;                  // 128 KB
    float*    beff = (float*)(ws + 128*1024);        // 1 KB
    float*    ao   = (float*)(ws + 132*1024);        // 512 KB

    prep_kernel<<<256, 256, 0, stream>>>(Wa, Wi, bi, bh, ba, Weff, beff);
    attn_kernel<<<B_SZ, 512, 0, stream>>>(x, Weff, beff, ao);
    lstm_kernel<<<128, 256, 0, stream>>>(ao, W_ih, b_ih, b_hh, (float*)d_out);
}

// Round 10
// 286.529 us; speedup vs baseline: 5.4900x; 1.0169x over previous
//
#include <hip/hip_runtime.h>
#include <hip/hip_bf16.h>

typedef _Float16 f16x8 __attribute__((ext_vector_type(8)));
typedef _Float16 f16x4 __attribute__((ext_vector_type(4)));
typedef float    f32x4 __attribute__((ext_vector_type(4)));

#define B_SZ 512
#define T_SZ 2048
#define D_SZ 256
#define TCHUNK 16
#define NCHUNK (T_SZ / TCHUNK)   // 128

// ---------- kernel 1: W_eff = -log2e * (Wa @ Wi) fp16; b_eff = -log2e * (Wa@(bi+bh) + ba)
__global__ __launch_bounds__(256) void prep_kernel(
    const float* __restrict__ Wa, const float* __restrict__ Wi,
    const float* __restrict__ bi, const float* __restrict__ bh,
    const float* __restrict__ ba,
    _Float16* __restrict__ Weff, float* __restrict__ beff)
{
    const float NL2E = -1.4426950408889634f;   // sigmoid(s) = 1/(1+exp2(NL2E*s))
    int e = blockIdx.x;      // output row (256)
    int d = threadIdx.x;     // output col (256)
    float a0 = 0.f, a1 = 0.f, a2 = 0.f, a3 = 0.f;
    #pragma unroll 4
    for (int k = 0; k < 256; k += 4) {
        a0 = fmaf(Wa[e*256 + k    ], Wi[(k    )*256 + d], a0);
        a1 = fmaf(Wa[e*256 + k + 1], Wi[(k + 1)*256 + d], a1);
        a2 = fmaf(Wa[e*256 + k + 2], Wi[(k + 2)*256 + d], a2);
        a3 = fmaf(Wa[e*256 + k + 3], Wi[(k + 3)*256 + d], a3);
    }
    Weff[e*256 + d] = (_Float16)(NL2E * ((a0 + a1) + (a2 + a3)));

    __shared__ float red[4];
    float s = Wa[e*256 + d] * (bi[d] + bh[d]);
    s += __shfl_down(s, 32, 64);
    s += __shfl_down(s, 16, 64);
    s += __shfl_down(s,  8, 64);
    s += __shfl_down(s,  4, 64);
    s += __shfl_down(s,  2, 64);
    s += __shfl_down(s,  1, 64);
    if ((d & 63) == 0) red[d >> 6] = s;
    __syncthreads();
    if (d == 0) beff[e] = NL2E * (ba[e] + ((red[0] + red[1]) + (red[2] + red[3])));
}

// ---------- kernel 2: fused GEMM + sigmoid + sum_t attn*x -> ao (B,256)
// EXACT r5 structure (264us control): 8 waves x 32 cols, swapped MFMA (S^T),
// fp16 LDS double-buffer 2x8KB, reg-staged coalesced loads, lgkm-only SYNC.
// r10 deltas vs r5 (issue-side only): (1) exp2-prescaled weights + bias folded
// into acc init; (2) LOADC issued BEFORE the barrier. NO chunk reversal
// (r9 showed it regresses DRAM streaming).
__global__ __launch_bounds__(512, 4) void attn_kernel(
    const float* __restrict__ x,          // (B, T, D)
    const _Float16* __restrict__ Weff,    // (256, 256) prescaled, row-major [e][k]
    const float* __restrict__ beff,       // (256) prescaled
    float* __restrict__ ao)               // (B, 256)
{
    const int b    = blockIdx.x;
    const int tid  = threadIdx.x;          // 0..511
    const int wave = tid >> 6;             // 0..7
    const int lane = tid & 63;
    const int l15  = lane & 15;
    const int lq   = lane >> 4;

    __shared__ _Float16 xs[2][TCHUNK * 256];  // 2 x 8 KB, swizzle: byte ^= (row&7)<<4
    char* xsb0 = reinterpret_cast<char*>(&xs[0][0]);
    char* xsb1 = reinterpret_cast<char*>(&xs[1][0]);

    // Weff fragments (A-operand after swap): lane holds Weff[e=base+l15][k=ks*32+lq*8+i]
    const int col0 = wave*32 + l15;
    const int col1 = col0 + 16;
    f16x8 bfA[8], bfB[8];
    #pragma unroll
    for (int ks = 0; ks < 8; ++ks) {
        bfA[ks] = *reinterpret_cast<const f16x8*>(&Weff[col0*256 + ks*32 + lq*8]);
        bfB[ks] = *reinterpret_cast<const f16x8*>(&Weff[col1*256 + ks*32 + lq*8]);
    }
    // bias per accumulator slot: e = wave*32 (+16) + lq*4 + r  (prescaled)
    const f32x4 bcA = *reinterpret_cast<const f32x4*>(&beff[wave*32 + lq*4]);
    const f32x4 bcB = *reinterpret_cast<const f32x4*>(&beff[wave*32 + 16 + lq*4]);

    const float* xb = x + (size_t)b * T_SZ * D_SZ;

    // staging: thread covers row = tid>>5 (0..15), 8 floats at col (tid&31)*8
    const int srow = tid >> 5;
    const int scg  = tid & 31;
    const float* srcp = xb + (size_t)srow * 256 + scg * 8;
    const int swb = (srow*512 + scg*16) ^ ((srow & 7) << 4);

    #define LOADC(R, c)                                                            \
        {                                                                          \
            const float* p = srcp + (size_t)(c) * (TCHUNK * D_SZ);                 \
            R##0 = *reinterpret_cast<const f32x4*>(p);                             \
            R##1 = *reinterpret_cast<const f32x4*>(p + 4);                         \
        }

    #define WRITE(BUF, R)                                                          \
        {                                                                          \
            f16x8 h;                                                               \
            h[0] = (_Float16)R##0[0]; h[1] = (_Float16)R##0[1];                    \
            h[2] = (_Float16)R##0[2]; h[3] = (_Float16)R##0[3];                    \
            h[4] = (_Float16)R##1[0]; h[5] = (_Float16)R##1[1];                    \
            h[6] = (_Float16)R##1[2]; h[7] = (_Float16)R##1[3];                    \
            *reinterpret_cast<f16x8*>((BUF) + swb) = h;                            \
        }

    // lgkm drain (my LDS ops done) -> barrier; does NOT drain vmcnt (prefetch lives)
    #define SYNC()                                                                 \
        {                                                                          \
            asm volatile("s_waitcnt lgkmcnt(0)" ::: "memory");                     \
            __builtin_amdgcn_sched_barrier(0);                                     \
            __builtin_amdgcn_s_barrier();                                          \
        }

    #define COMPUTE(BUF)                                                           \
        {                                                                          \
            const int aswz  = (l15 & 7) << 4;                                      \
            const int abase = l15 * 512;                                           \
            f32x4 acc0 = bcA;                                                      \
            f32x4 acc1 = bcB;                                                      \
            _Pragma("unroll")                                                      \
            for (int ks = 0; ks < 8; ++ks) {                                       \
                int ab = abase + ((ks*64 + lq*16) ^ aswz);                         \
                f16x8 a = *reinterpret_cast<const f16x8*>((BUF) + ab);             \
                acc0 = __builtin_amdgcn_mfma_f32_16x16x32_f16(bfA[ks], a, acc0, 0, 0, 0); \
                acc1 = __builtin_amdgcn_mfma_f32_16x16x32_f16(bfB[ks], a, acc1, 0, 0, 0); \
            }                                                                      \
            /* epilogue: lane has t = l15, e = wave*32 (+16) + lq*4 + r */         \
            int eb0 = abase + (((wave*64      ) + lq*8) ^ aswz);                   \
            int eb1 = abase + (((wave*64 + 32 ) + lq*8) ^ aswz);                   \
            f16x4 xq0 = *reinterpret_cast<const f16x4*>((BUF) + eb0);              \
            f16x4 xq1 = *reinterpret_cast<const f16x4*>((BUF) + eb1);              \
            _Pragma("unroll")                                                      \
            for (int r = 0; r < 4; ++r) {                                          \
                {                                                                  \
                    float attn = __builtin_amdgcn_rcpf(1.f + exp2f(acc0[r]));      \
                    ao0[r] = fmaf(attn, (float)xq0[r], ao0[r]);                    \
                }                                                                  \
                {                                                                  \
                    float attn = __builtin_amdgcn_rcpf(1.f + exp2f(acc1[r]));      \
                    ao1[r] = fmaf(attn, (float)xq1[r], ao1[r]);                    \
                }                                                                  \
            }                                                                      \
        }

    f32x4 ao0 = {0.f, 0.f, 0.f, 0.f};
    f32x4 ao1 = {0.f, 0.f, 0.f, 0.f};
    f32x4 sA0, sA1, sB0, sB1;

    LOADC(sA, 0);
    LOADC(sB, 1);

    for (int c = 0; c < NCHUNK; c += 2) {
        WRITE(xsb0, sA);                 // vmcnt-waits sA only; sA regs dead after cvt
        if (c + 2 < NCHUNK) LOADC(sA, c + 2);   // issue BEFORE barrier
        SYNC();                          // chunk c visible to all waves
        COMPUTE(xsb0);                   // chunk c
        WRITE(xsb1, sB);                 // other buffer: safe while others compute xsb0
        if (c + 3 < NCHUNK) LOADC(sB, c + 3);
        SYNC();                          // chunk c+1 visible
        COMPUTE(xsb1);                   // chunk c+1
    }

    // sum over t: reduce across l15 within each lq group
    #pragma unroll
    for (int m = 1; m <= 8; m <<= 1) {
        #pragma unroll
        for (int r = 0; r < 4; ++r) {
            ao0[r] += __shfl_xor(ao0[r], m, 64);
            ao1[r] += __shfl_xor(ao1[r], m, 64);
        }
    }
    if (l15 == 0) {
        *reinterpret_cast<f32x4*>(&ao[b*256 + wave*32 +      lq*4]) = ao0;
        *reinterpret_cast<f32x4*>(&ao[b*256 + wave*32 + 16 + lq*4]) = ao1;
    }

    #undef LOADC
    #undef WRITE
    #undef SYNC
    #undef COMPUTE
}

// ---------- kernel 3: LSTM cell (h0=c0=0 => f gate dead, W_hh dead)
// 128 blocks x 4 batches: W_ih rows loaded once per block, reused across 4 batches.
__global__ __launch_bounds__(256) void lstm_kernel(
    const float* __restrict__ ao,        // (B, 256)
    const float* __restrict__ Wih,       // (1024, 256)
    const float* __restrict__ bih,       // (1024)
    const float* __restrict__ bhh,       // (1024)
    float* __restrict__ out)             // h (B*256) | h (B*256) | c (B*256)
{
    const int b0 = blockIdx.x * 4;   // 128 blocks
    const int j  = threadIdx.x;      // 256
    __shared__ float a[4][256];
    #pragma unroll
    for (int bb = 0; bb < 4; ++bb) a[bb][j] = ao[(b0 + bb)*256 + j];
    __syncthreads();

    const float bi_ = bih[j]       + bhh[j];
    const float bg_ = bih[512 + j] + bhh[512 + j];
    const float bo_ = bih[768 + j] + bhh[768 + j];
    float gi[4], gg[4], go[4];
    #pragma unroll
    for (int bb = 0; bb < 4; ++bb) { gi[bb] = bi_; gg[bb] = bg_; go[bb] = bo_; }

    const float* wi = Wih + (size_t)j * 256;
    const float* wg = Wih + (size_t)(512 + j) * 256;
    const float* wo = Wih + (size_t)(768 + j) * 256;
    #pragma unroll 2
    for (int k = 0; k < 256; k += 4) {
        f32x4 w1 = *reinterpret_cast<const f32x4*>(wi + k);
        f32x4 w2 = *reinterpret_cast<const f32x4*>(wg + k);
        f32x4 w3 = *reinterpret_cast<const f32x4*>(wo + k);
        f32x4 av0 = *reinterpret_cast<const f32x4*>(&a[0][k]);
        f32x4 av1 = *reinterpret_cast<const f32x4*>(&a[1][k]);
        f32x4 av2 = *reinterpret_cast<const f32x4*>(&a[2][k]);
        f32x4 av3 = *reinterpret_cast<const f32x4*>(&a[3][k]);
        #pragma unroll
        for (int q = 0; q < 4; ++q) {
            gi[0] = fmaf(w1[q], av0[q], gi[0]); gg[0] = fmaf(w2[q], av0[q], gg[0]); go[0] = fmaf(w3[q], av0[q], go[0]);
            gi[1] = fmaf(w1[q], av1[q], gi[1]); gg[1] = fmaf(w2[q], av1[q], gg[1]); go[1] = fmaf(w3[q], av1[q], go[1]);
            gi[2] = fmaf(w1[q], av2[q], gi[2]); gg[2] = fmaf(w2[q], av2[q], gg[2]); go[2] = fmaf(w3[q], av2[q], go[2]);
            gi[3] = fmaf(w1[q], av3[q], gi[3]); gg[3] = fmaf(w2[q], av3[q], gg[3]); go[3] = fmaf(w3[q], av3[q], go[3]);
        }
    }

    #pragma unroll
    for (int bb = 0; bb < 4; ++bb) {
        float ig = 1.f / (1.f + __expf(-gi[bb]));
        float g  = tanhf(gg[bb]);
        float og = 1.f / (1.f + __expf(-go[bb]));
        float cc = ig * g;
        float hh = og * tanhf(cc);
        out[          (b0 + bb)*256 + j] = hh;
        out[131072 +  (b0 + bb)*256 + j] = hh;
        out[262144 +  (b0 + bb)*256 + j] = cc;
    }
}

extern "C" void kernel_launch(void* const* d_in, const int* in_sizes, int n_in,
                              void* d_out, int out_size, void* d_ws, size_t ws_size,
                              hipStream_t stream) {
    const float* x    = (const float*)d_in[0];
    const float* Wi   = (const float*)d_in[1];
    const float* bi   = (const float*)d_in[2];
    // d_in[3] = Wh (dead: h0 = 0)
    const float* bh   = (const float*)d_in[4];
    const float* Wa   = (const float*)d_in[5];
    const float* ba   = (const float*)d_in[6];
    const float* W_ih = (const float*)d_in[7];
    const float* b_ih = (const float*)d_in[8];
    // d_in[9] = W_hh (dead: h0 = 0)
    const float* b_hh = (const float*)d_in[10];

    char* ws = (char*)d_ws;
    _Float16* Weff = (_Float16*)ws;                  // 128 KB
    float*    beff = (float*)(ws + 128*1024);        // 1 KB
    float*    ao   = (float*)(ws + 132*1024);        // 512 KB

    prep_kernel<<<256, 256, 0, stream>>>(Wa, Wi, bi, bh, ba, Weff, beff);
    attn_kernel<<<B_SZ, 512, 0, stream>>>(x, Weff, beff, ao);
    lstm_kernel<<<128, 256, 0, stream>>>(ao, W_ih, b_ih, b_hh, (float*)d_out);
}

// Round 11
// 273.338 us; speedup vs baseline: 5.7550x; 1.0483x over previous
//
#include <hip/hip_runtime.h>
#include <hip/hip_bf16.h>

typedef _Float16 f16x8 __attribute__((ext_vector_type(8)));
typedef _Float16 f16x4 __attribute__((ext_vector_type(4)));
typedef float    f32x4 __attribute__((ext_vector_type(4)));

#define B_SZ 512
#define T_SZ 2048
#define D_SZ 256
#define TCHUNK 16
#define NCH2 64            // chunks per half-block (T/2 / TCHUNK)

// ---------- kernel 1: W_eff[e,k] = sum_d Wa[e,d]*Wi[d,k];  b_eff[e] = Wa[e,:]@(bi+bh) + ba[e]
// (r5 original) + zero ao for the attn atomics.
__global__ __launch_bounds__(256) void prep_kernel(
    const float* __restrict__ Wa, const float* __restrict__ Wi,
    const float* __restrict__ bi, const float* __restrict__ bh,
    const float* __restrict__ ba,
    _Float16* __restrict__ Weff, float* __restrict__ beff,
    float* __restrict__ ao)
{
    int e = blockIdx.x;      // output row (256)
    int d = threadIdx.x;     // output col (256)
    float a0 = 0.f, a1 = 0.f, a2 = 0.f, a3 = 0.f;
    #pragma unroll 4
    for (int k = 0; k < 256; k += 4) {
        a0 = fmaf(Wa[e*256 + k    ], Wi[(k    )*256 + d], a0);
        a1 = fmaf(Wa[e*256 + k + 1], Wi[(k + 1)*256 + d], a1);
        a2 = fmaf(Wa[e*256 + k + 2], Wi[(k + 2)*256 + d], a2);
        a3 = fmaf(Wa[e*256 + k + 3], Wi[(k + 3)*256 + d], a3);
    }
    Weff[e*256 + d] = (_Float16)((a0 + a1) + (a2 + a3));

    // zero ao (131072 floats; 65536 threads x 2)
    int gt = e*256 + d;
    ao[gt*2] = 0.f; ao[gt*2 + 1] = 0.f;

    __shared__ float red[4];
    float s = Wa[e*256 + d] * (bi[d] + bh[d]);
    s += __shfl_down(s, 32, 64);
    s += __shfl_down(s, 16, 64);
    s += __shfl_down(s,  8, 64);
    s += __shfl_down(s,  4, 64);
    s += __shfl_down(s,  2, 64);
    s += __shfl_down(s,  1, 64);
    if ((d & 63) == 0) red[d >> 6] = s;
    __syncthreads();
    if (d == 0) beff[e] = ba[e] + ((red[0] + red[1]) + (red[2] + red[3]));
}

// ---------- kernel 2: fused GEMM + sigmoid + sum_t attn*x -> ao (B,256)
// EXACT r5 structure/math (264us control). SINGLE delta: T-split occupancy —
// each batch is covered by TWO blocks (disjoint 1024-row halves), grid=1024,
// 4 blocks/CU = 32 waves/CU (max), 4 independent barrier domains per CU.
// Partials combined via atomicAdd into prep-zeroed ao.
__global__ __launch_bounds__(512, 4) void attn_kernel(
    const float* __restrict__ x,          // (B, T, D)
    const _Float16* __restrict__ Weff,    // (256, 256) row-major [e][k]
    const float* __restrict__ beff,       // (256)
    float* __restrict__ ao)               // (B, 256), pre-zeroed
{
    const int b    = blockIdx.x >> 1;      // batch
    const int th   = blockIdx.x & 1;       // T-half
    const int tid  = threadIdx.x;          // 0..511
    const int wave = tid >> 6;             // 0..7
    const int lane = tid & 63;
    const int l15  = lane & 15;
    const int lq   = lane >> 4;

    __shared__ _Float16 xs[2][TCHUNK * 256];  // 2 x 8 KB, swizzle: byte ^= (row&7)<<4
    char* xsb0 = reinterpret_cast<char*>(&xs[0][0]);
    char* xsb1 = reinterpret_cast<char*>(&xs[1][0]);

    // Weff fragments (A-operand after swap): lane holds Weff[e=base+l15][k=ks*32+lq*8+i]
    const int col0 = wave*32 + l15;
    const int col1 = col0 + 16;
    f16x8 bfA[8], bfB[8];
    #pragma unroll
    for (int ks = 0; ks < 8; ++ks) {
        bfA[ks] = *reinterpret_cast<const f16x8*>(&Weff[col0*256 + ks*32 + lq*8]);
        bfB[ks] = *reinterpret_cast<const f16x8*>(&Weff[col1*256 + ks*32 + lq*8]);
    }
    // bias per accumulator slot: e = wave*32 (+16) + lq*4 + r
    const f32x4 bcA = *reinterpret_cast<const f32x4*>(&beff[wave*32 + lq*4]);
    const f32x4 bcB = *reinterpret_cast<const f32x4*>(&beff[wave*32 + 16 + lq*4]);

    const float* xb = x + (size_t)b * T_SZ * D_SZ + (size_t)th * (T_SZ/2) * D_SZ;

    // staging: thread covers row = tid>>5 (0..15), 8 floats at col (tid&31)*8
    const int srow = tid >> 5;
    const int scg  = tid & 31;
    const float* srcp = xb + (size_t)srow * 256 + scg * 8;
    const int swb = (srow*512 + scg*16) ^ ((srow & 7) << 4);

    #define LOADC(R, c)                                                            \
        {                                                                          \
            const float* p = srcp + (size_t)(c) * (TCHUNK * D_SZ);                 \
            R##0 = *reinterpret_cast<const f32x4*>(p);                             \
            R##1 = *reinterpret_cast<const f32x4*>(p + 4);                         \
        }

    #define WRITE(BUF, R)                                                          \
        {                                                                          \
            f16x8 h;                                                               \
            h[0] = (_Float16)R##0[0]; h[1] = (_Float16)R##0[1];                    \
            h[2] = (_Float16)R##0[2]; h[3] = (_Float16)R##0[3];                    \
            h[4] = (_Float16)R##1[0]; h[5] = (_Float16)R##1[1];                    \
            h[6] = (_Float16)R##1[2]; h[7] = (_Float16)R##1[3];                    \
            *reinterpret_cast<f16x8*>((BUF) + swb) = h;                            \
        }

    // lgkm drain (my LDS ops done) -> barrier; does NOT drain vmcnt (prefetch lives)
    #define SYNC()                                                                 \
        {                                                                          \
            asm volatile("s_waitcnt lgkmcnt(0)" ::: "memory");                     \
            __builtin_amdgcn_sched_barrier(0);                                     \
            __builtin_amdgcn_s_barrier();                                          \
        }

    #define COMPUTE(BUF)                                                           \
        {                                                                          \
            const int aswz  = (l15 & 7) << 4;                                      \
            const int abase = l15 * 512;                                           \
            f32x4 acc0 = {0.f, 0.f, 0.f, 0.f};                                     \
            f32x4 acc1 = {0.f, 0.f, 0.f, 0.f};                                     \
            _Pragma("unroll")                                                      \
            for (int ks = 0; ks < 8; ++ks) {                                       \
                int ab = abase + ((ks*64 + lq*16) ^ aswz);                         \
                f16x8 a = *reinterpret_cast<const f16x8*>((BUF) + ab);             \
                acc0 = __builtin_amdgcn_mfma_f32_16x16x32_f16(bfA[ks], a, acc0, 0, 0, 0); \
                acc1 = __builtin_amdgcn_mfma_f32_16x16x32_f16(bfB[ks], a, acc1, 0, 0, 0); \
            }                                                                      \
            /* epilogue: lane has t = l15, e = wave*32 (+16) + lq*4 + r */         \
            int eb0 = abase + (((wave*64      ) + lq*8) ^ aswz);                   \
            int eb1 = abase + (((wave*64 + 32 ) + lq*8) ^ aswz);                   \
            f16x4 xq0 = *reinterpret_cast<const f16x4*>((BUF) + eb0);              \
            f16x4 xq1 = *reinterpret_cast<const f16x4*>((BUF) + eb1);              \
            _Pragma("unroll")                                                      \
            for (int r = 0; r < 4; ++r) {                                          \
                {                                                                  \
                    float s = acc0[r] + bcA[r];                                    \
                    float attn = __builtin_amdgcn_rcpf(1.f + __expf(-s));          \
                    ao0[r] = fmaf(attn, (float)xq0[r], ao0[r]);                    \
                }                                                                  \
                {                                                                  \
                    float s = acc1[r] + bcB[r];                                    \
                    float attn = __builtin_amdgcn_rcpf(1.f + __expf(-s));          \
                    ao1[r] = fmaf(attn, (float)xq1[r], ao1[r]);                    \
                }                                                                  \
            }                                                                      \
        }

    f32x4 ao0 = {0.f, 0.f, 0.f, 0.f};
    f32x4 ao1 = {0.f, 0.f, 0.f, 0.f};
    f32x4 sA0, sA1, sB0, sB1;

    LOADC(sA, 0);
    LOADC(sB, 1);

    for (int c = 0; c < NCH2; c += 2) {
        WRITE(xsb0, sA);                 // vmcnt-waits sA only
        SYNC();                          // chunk c visible to all waves
        if (c + 2 < NCH2) LOADC(sA, c + 2);
        COMPUTE(xsb0);                   // chunk c
        WRITE(xsb1, sB);                 // other buffer: safe while others compute xsb0
        SYNC();                          // chunk c+1 visible
        if (c + 3 < NCH2) LOADC(sB, c + 3);
        COMPUTE(xsb1);                   // chunk c+1
    }

    // sum over t: reduce across l15 within each lq group; combine halves via atomics
    #pragma unroll
    for (int m = 1; m <= 8; m <<= 1) {
        #pragma unroll
        for (int r = 0; r < 4; ++r) {
            ao0[r] += __shfl_xor(ao0[r], m, 64);
            ao1[r] += __shfl_xor(ao1[r], m, 64);
        }
    }
    if (l15 == 0) {
        #pragma unroll
        for (int r = 0; r < 4; ++r) {
            atomicAdd(&ao[b*256 + wave*32 +      lq*4 + r], ao0[r]);
            atomicAdd(&ao[b*256 + wave*32 + 16 + lq*4 + r], ao1[r]);
        }
    }

    #undef LOADC
    #undef WRITE
    #undef SYNC
    #undef COMPUTE
}

// ---------- kernel 3: LSTM cell (h0=c0=0 => f gate dead, W_hh dead)  [r5 original]
__global__ __launch_bounds__(256) void lstm_kernel(
    const float* __restrict__ ao,        // (B, 256)
    const float* __restrict__ Wih,       // (1024, 256)
    const float* __restrict__ bih,       // (1024)
    const float* __restrict__ bhh,       // (1024)
    float* __restrict__ out)             // h (B*256) | h (B*256) | c (B*256)
{
    int b = blockIdx.x;    // 512
    int j = threadIdx.x;   // 256
    __shared__ float a[256];
    a[j] = ao[b*256 + j];
    __syncthreads();

    float gi = bih[j]       + bhh[j];
    float gg = bih[512 + j] + bhh[512 + j];
    float go = bih[768 + j] + bhh[768 + j];
    const float* wi = Wih + (size_t)j * 256;
    const float* wg = Wih + (size_t)(512 + j) * 256;
    const float* wo = Wih + (size_t)(768 + j) * 256;
    #pragma unroll 4
    for (int k = 0; k < 256; k += 4) {
        f32x4 w1 = *reinterpret_cast<const f32x4*>(wi + k);
        f32x4 w2 = *reinterpret_cast<const f32x4*>(wg + k);
        f32x4 w3 = *reinterpret_cast<const f32x4*>(wo + k);
        #pragma unroll
        for (int q = 0; q < 4; ++q) {
            float av = a[k + q];
            gi = fmaf(w1[q], av, gi);
            gg = fmaf(w2[q], av, gg);
            go = fmaf(w3[q], av, go);
        }
    }
    float ig = 1.f / (1.f + __expf(-gi));
    float g  = tanhf(gg);
    float og = 1.f / (1.f + __expf(-go));
    float cc = ig * g;
    float hh = og * tanhf(cc);
    out[          b*256 + j] = hh;
    out[131072 +  b*256 + j] = hh;
    out[262144 +  b*256 + j] = cc;
}

extern "C" void kernel_launch(void* const* d_in, const int* in_sizes, int n_in,
                              void* d_out, int out_size, void* d_ws, size_t ws_size,
                              hipStream_t stream) {
    const float* x    = (const float*)d_in[0];
    const float* Wi   = (const float*)d_in[1];
    const float* bi   = (const float*)d_in[2];
    // d_in[3] = Wh (dead: h0 = 0)
    const float* bh   = (const float*)d_in[4];
    const float* Wa   = (const float*)d_in[5];
    const float* ba   = (const float*)d_in[6];
    const float* W_ih = (const float*)d_in[7];
    const float* b_ih = (const float*)d_in[8];
    // d_in[9] = W_hh (dead: h0 = 0)
    const float* b_hh = (const float*)d_in[10];

    char* ws = (char*)d_ws;
    _Float16* Weff = (_Float16*)ws;                  // 128 KB
    float*    beff = (float*)(ws + 128*1024);        // 1 KB
    float*    ao   = (float*)(ws + 132*1024);        // 512 KB

    prep_kernel<<<256, 256, 0, stream>>>(Wa, Wi, bi, bh, ba, Weff, beff, ao);
    attn_kernel<<<2 * B_SZ, 512, 0, stream>>>(x, Weff, beff, ao);
    lstm_kernel<<<B_SZ, 256, 0, stream>>>(ao, W_ih, b_ih, b_hh, (float*)d_out);
}